// Round 1
// baseline (563.243 us; speedup 1.0000x reference)
//
#include <hip/hip_runtime.h>

typedef unsigned short u16;
typedef __attribute__((ext_vector_type(4))) float f32x4;
typedef __attribute__((ext_vector_type(8))) short bf16x8;

#define DEV static __device__ __forceinline__

DEV float bf2f(u16 u) { unsigned int i = ((unsigned int)u) << 16; return __builtin_bit_cast(float, i); }
DEV u16 f2bf(float f) {
  unsigned int x = __builtin_bit_cast(unsigned int, f);
  x += 0x7fffu + ((x >> 16) & 1u);
  return (u16)(x >> 16);
}

DEV void gload16(const u16* g, u16* l) {
  __builtin_amdgcn_global_load_lds(
      (const __attribute__((address_space(1))) unsigned int*)g,
      (__attribute__((address_space(3))) unsigned int*)l, 16, 0, 0);
}

// ---------------- LayerNorm: fp32 in -> bf16 out (D=1024, one block per row) ----------------
__global__ __launch_bounds__(256) void ln_k(const float* __restrict__ x,
                                            const float* __restrict__ g,
                                            const float* __restrict__ b,
                                            u16* __restrict__ out) {
  const int row = blockIdx.x;
  const int t = threadIdx.x;
  const float4 v = *(const float4*)(x + (size_t)row * 1024 + t * 4);
  float s = v.x + v.y + v.z + v.w;
  float q = v.x * v.x + v.y * v.y + v.z * v.z + v.w * v.w;
#pragma unroll
  for (int m = 1; m < 64; m <<= 1) { s += __shfl_xor(s, m); q += __shfl_xor(q, m); }
  __shared__ float ss[4], qs[4];
  if ((t & 63) == 0) { ss[t >> 6] = s; qs[t >> 6] = q; }
  __syncthreads();
  s = ss[0] + ss[1] + ss[2] + ss[3];
  q = qs[0] + qs[1] + qs[2] + qs[3];
  const float mean = s * (1.0f / 1024.0f);
  const float var = q * (1.0f / 1024.0f) - mean * mean;
  const float rs = rsqrtf(var + 1e-6f);
  const float4 gv = *(const float4*)(g + t * 4);
  const float4 bv = *(const float4*)(b + t * 4);
  ushort4 o;
  o.x = f2bf((v.x - mean) * rs * gv.x + bv.x);
  o.y = f2bf((v.y - mean) * rs * gv.y + bv.y);
  o.z = f2bf((v.z - mean) * rs * gv.z + bv.z);
  o.w = f2bf((v.w - mean) * rs * gv.w + bv.w);
  *(ushort4*)(out + (size_t)row * 1024 + t * 4) = o;
}

// ---------------- weight transpose + cvt: src (K x N) f32 -> dst (N x K) bf16 ----------------
__global__ __launch_bounds__(256) void tcvt_k(const float* __restrict__ src,
                                              u16* __restrict__ dst, int K, int N) {
  __shared__ u16 tl[32][33];
  const int k0 = blockIdx.x * 32, n0 = blockIdx.y * 32;
  const int c = threadIdx.x & 31, r0 = threadIdx.x >> 5;
#pragma unroll
  for (int p = 0; p < 4; p++) {
    const int r = p * 8 + r0;
    tl[r][c] = f2bf(src[(size_t)(k0 + r) * N + n0 + c]);
  }
  __syncthreads();
#pragma unroll
  for (int p = 0; p < 4; p++) {
    const int r = p * 8 + r0;
    dst[(size_t)(n0 + r) * K + k0 + c] = tl[c][r];
  }
}

// ---------------- GEMM: C(MxN) = A(MxK,bf16) @ Bt(NxK,bf16)^T, fused epilogues ----------------
// EPI 0: out bf16 = acc + bias
// EPI 1: out bf16 = gelu(acc + bias)
// EPI 2: out f32  = resid + gate[col]*(acc + bias)
// EPI 3: out f32 += gate[col]*(acc + bias)
template <int EPI>
__global__ __launch_bounds__(256) void gemm_bt(const u16* __restrict__ A,
                                               const u16* __restrict__ Bt,
                                               const float* __restrict__ bias,
                                               const float* __restrict__ resid,
                                               const float* __restrict__ gate,
                                               void* __restrict__ outv,
                                               int M, int N, int K) {
  __shared__ u16 lA[128 * 32];
  __shared__ u16 lB[128 * 32];
  const int tid = threadIdx.x;
  const int lane = tid & 63, wid = tid >> 6;
  const int l4 = lane >> 4, l15 = lane & 15;
  const int wr = wid >> 1, wc = wid & 1;
  const int mBase = blockIdx.x * 128;
  const int nBase = blockIdx.y * 128;

  f32x4 acc[4][4];
#pragma unroll
  for (int i = 0; i < 4; i++)
#pragma unroll
    for (int j = 0; j < 4; j++)
#pragma unroll
      for (int e = 0; e < 4; e++) acc[i][j][e] = 0.f;

  const int sRow = tid >> 2;
  const int sCol = (tid & 3) * 8;

  for (int k0 = 0; k0 < K; k0 += 32) {
#pragma unroll
    for (int r2 = 0; r2 < 2; r2++) {
      gload16(A + (size_t)(mBase + r2 * 64 + sRow) * K + k0 + sCol, lA + r2 * 2048 + wid * 512);
      gload16(Bt + (size_t)(nBase + r2 * 64 + sRow) * K + k0 + sCol, lB + r2 * 2048 + wid * 512);
    }
    __syncthreads();
    bf16x8 af[4], bf[4];
#pragma unroll
    for (int mi = 0; mi < 4; mi++)
      af[mi] = *(const bf16x8*)(lA + (wr * 64 + mi * 16 + l15) * 32 + l4 * 8);
#pragma unroll
    for (int ni = 0; ni < 4; ni++)
      bf[ni] = *(const bf16x8*)(lB + (wc * 64 + ni * 16 + l15) * 32 + l4 * 8);
#pragma unroll
    for (int mi = 0; mi < 4; mi++)
#pragma unroll
      for (int ni = 0; ni < 4; ni++)
        acc[mi][ni] = __builtin_amdgcn_mfma_f32_16x16x32_bf16(af[mi], bf[ni], acc[mi][ni], 0, 0, 0);
    __syncthreads();
  }

  u16* obf = (u16*)outv;
  float* of = (float*)outv;
#pragma unroll
  for (int mi = 0; mi < 4; mi++) {
#pragma unroll
    for (int ni = 0; ni < 4; ni++) {
      const int row0 = mBase + wr * 64 + mi * 16 + l4 * 4;
      const int col = nBase + wc * 64 + ni * 16 + l15;
      const float bb = bias[col];
#pragma unroll
      for (int r = 0; r < 4; r++) {
        const float v = acc[mi][ni][r] + bb;
        const size_t idx = (size_t)(row0 + r) * N + col;
        if (EPI == 0) {
          obf[idx] = f2bf(v);
        } else if (EPI == 1) {
          const float ge = 0.5f * v * (1.0f + erff(v * 0.70710678118654752f));
          obf[idx] = f2bf(ge);
        } else if (EPI == 2) {
          of[idx] = resid[idx] + gate[col] * v;
        } else {
          of[idx] = of[idx] + gate[col] * v;
        }
      }
    }
  }
}

// ---------------- RoPE + head-layout: qkv(4096x3072 bf16) -> q_r/k_r (B,H,L,hd) bf16 ----------------
__global__ __launch_bounds__(256) void rope_k(const u16* __restrict__ qkv,
                                              u16* __restrict__ qr, u16* __restrict__ kr) {
  const int sel = blockIdx.y;  // 0 -> q, 1 -> k
  const int rid = blockIdx.x * 8 + (threadIdx.x >> 5);  // (b,h,t) row id, 0..65535
  const int i = threadIdx.x & 31;                       // pair index 0..31
  const int b = rid >> 15;
  const int h = (rid >> 11) & 15;
  const int t = rid & 2047;
  const u16* src = qkv + (size_t)(b * 2048 + t) * 3072 + sel * 1024 + h * 64 + 2 * i;
  const ushort2 uv = *(const ushort2*)src;
  const float x0 = bf2f(uv.x), x1 = bf2f(uv.y);
  const float inv = __expf(-(float)i * 0.28782313662425572f);  // ln(10000)/32
  float sn, cs;
  sincosf((float)t * inv, &sn, &cs);
  ushort2 ov;
  ov.x = f2bf(x0 * cs - x1 * sn);
  ov.y = f2bf(x1 * cs + x0 * sn);
  *(ushort2*)((sel ? kr : qr) + (size_t)rid * 64 + 2 * i) = ov;
}

// ---------------- V layout: qkv cols 2048.. -> v_t (B,H,hd,L) bf16 (transposed) ----------------
__global__ __launch_bounds__(256) void vtrans_k(const u16* __restrict__ qkv, u16* __restrict__ vt) {
  __shared__ u16 tl[64][65];
  const int bh = blockIdx.x >> 5;
  const int t0 = (blockIdx.x & 31) * 64;
  const int b = bh >> 4, h = bh & 15;
  const int tid = threadIdx.x;
#pragma unroll
  for (int p = 0; p < 16; p++) {
    const int e = p * 256 + tid;
    const int tr = e >> 6, d = e & 63;
    tl[tr][d] = qkv[(size_t)(b * 2048 + t0 + tr) * 3072 + 2048 + h * 64 + d];
  }
  __syncthreads();
#pragma unroll
  for (int p = 0; p < 16; p++) {
    const int e = p * 256 + tid;
    const int dr = e >> 6, tc = e & 63;
    vt[(size_t)(bh * 64 + dr) * 2048 + t0 + tc] = tl[tc][dr];
  }
}

// ---------------- Flash attention: 4 waves/block, 16 q-rows/wave, KVBLK=64 ----------------
// q,k: (B,H,L,hd) bf16 ; vt: (B,H,hd,L) bf16 ; o: (B,L,D) bf16
__global__ __launch_bounds__(256) void attn_k(const u16* __restrict__ q,
                                              const u16* __restrict__ k,
                                              const u16* __restrict__ vt,
                                              u16* __restrict__ o) {
  const int bh = blockIdx.y;
  const int wid = threadIdx.x >> 6, lane = threadIdx.x & 63;
  const int l4 = lane >> 4, l15 = lane & 15;
  const int qrow0 = blockIdx.x * 64 + wid * 16;
  const size_t qoff = ((size_t)bh * 2048 + qrow0) * 64;
  const bf16x8 qf0 = *(const bf16x8*)(q + qoff + l15 * 64 + l4 * 8);
  const bf16x8 qf1 = *(const bf16x8*)(q + qoff + l15 * 64 + 32 + l4 * 8);
  float m[4], lsum[4];
  f32x4 oacc[4];
#pragma unroll
  for (int r = 0; r < 4; r++) { m[r] = -1e30f; lsum[r] = 0.f; }
#pragma unroll
  for (int ni = 0; ni < 4; ni++)
#pragma unroll
    for (int e = 0; e < 4; e++) oacc[ni][e] = 0.f;

  __shared__ u16 plds[4][16][80];   // stride 80 -> 160B rows (16B-aligned b128 reads)
  u16(*P)[80] = plds[wid];
  const u16* kbase = k + (size_t)bh * 2048 * 64;
  const u16* vbase = vt + (size_t)bh * 64 * 2048;

  for (int kv = 0; kv < 2048; kv += 64) {
    f32x4 s[4];
#pragma unroll
    for (int kt = 0; kt < 4; kt++) {
      const u16* kb = kbase + (size_t)(kv + kt * 16 + l15) * 64 + l4 * 8;
      const bf16x8 kf0 = *(const bf16x8*)kb;
      const bf16x8 kf1 = *(const bf16x8*)(kb + 32);
      f32x4 z;
      z[0] = 0.f; z[1] = 0.f; z[2] = 0.f; z[3] = 0.f;
      z = __builtin_amdgcn_mfma_f32_16x16x32_bf16(qf0, kf0, z, 0, 0, 0);
      s[kt] = __builtin_amdgcn_mfma_f32_16x16x32_bf16(qf1, kf1, z, 0, 0, 0);
    }
#pragma unroll
    for (int r = 0; r < 4; r++) {
      const float sv0 = s[0][r] * 0.125f, sv1 = s[1][r] * 0.125f;
      const float sv2 = s[2][r] * 0.125f, sv3 = s[3][r] * 0.125f;
      float mx = fmaxf(fmaxf(sv0, sv1), fmaxf(sv2, sv3));
#pragma unroll
      for (int d = 1; d < 16; d <<= 1) mx = fmaxf(mx, __shfl_xor(mx, d));
      const float mn = fmaxf(m[r], mx);
      const float al = __expf(m[r] - mn);
      m[r] = mn;
      const float p0 = __expf(sv0 - mn), p1 = __expf(sv1 - mn);
      const float p2 = __expf(sv2 - mn), p3 = __expf(sv3 - mn);
      float ps = p0 + p1 + p2 + p3;
#pragma unroll
      for (int d = 1; d < 16; d <<= 1) ps += __shfl_xor(ps, d);
      lsum[r] = lsum[r] * al + ps;
#pragma unroll
      for (int ni = 0; ni < 4; ni++) oacc[ni][r] *= al;
      const int prow = l4 * 4 + r;
      // XOR-swizzled columns: stored col = col ^ (row>>2)<<4 -> write is 2 lanes/bank (free)
      P[prow][(0 ^ l4) * 16 + l15] = f2bf(p0);
      P[prow][(1 ^ l4) * 16 + l15] = f2bf(p1);
      P[prow][(2 ^ l4) * 16 + l15] = f2bf(p2);
      P[prow][(3 ^ l4) * 16 + l15] = f2bf(p3);
    }
    asm volatile("s_waitcnt lgkmcnt(0)" ::: "memory");
    const int swz = (l15 >> 2) << 4;
    const bf16x8 pa0 = *(const bf16x8*)(&P[l15][(l4 * 8) ^ swz]);
    const bf16x8 pa1 = *(const bf16x8*)(&P[l15][(32 + l4 * 8) ^ swz]);
#pragma unroll
    for (int ni = 0; ni < 4; ni++) {
      const u16* vb = vbase + (size_t)(ni * 16 + l15) * 2048 + kv + l4 * 8;
      const bf16x8 v0 = *(const bf16x8*)vb;
      const bf16x8 v1 = *(const bf16x8*)(vb + 32);
      oacc[ni] = __builtin_amdgcn_mfma_f32_16x16x32_bf16(pa0, v0, oacc[ni], 0, 0, 0);
      oacc[ni] = __builtin_amdgcn_mfma_f32_16x16x32_bf16(pa1, v1, oacc[ni], 0, 0, 0);
    }
  }
  const int b = bh >> 4, h = bh & 15;
#pragma unroll
  for (int r = 0; r < 4; r++) {
    const size_t row = (size_t)b * 2048 + qrow0 + l4 * 4 + r;
    const float iv = 1.0f / lsum[r];
#pragma unroll
    for (int ni = 0; ni < 4; ni++)
      o[row * 1024 + h * 64 + ni * 16 + l15] = f2bf(oacc[ni][r] * iv);
  }
}

extern "C" void kernel_launch(void* const* d_in, const int* in_sizes, int n_in,
                              void* d_out, int out_size, void* d_ws, size_t ws_size,
                              hipStream_t stream) {
  (void)in_sizes; (void)n_in; (void)out_size; (void)ws_size;
  const float* x     = (const float*)d_in[0];
  const float* ln1_g = (const float*)d_in[1];
  const float* ln1_b = (const float*)d_in[2];
  const float* wq    = (const float*)d_in[3];
  const float* bq    = (const float*)d_in[4];
  const float* wk    = (const float*)d_in[5];
  const float* bk    = (const float*)d_in[6];
  const float* wv    = (const float*)d_in[7];
  const float* bv    = (const float*)d_in[8];
  const float* wo    = (const float*)d_in[9];
  const float* bo    = (const float*)d_in[10];
  const float* ln2_g = (const float*)d_in[11];
  const float* ln2_b = (const float*)d_in[12];
  const float* w1    = (const float*)d_in[13];
  const float* b1    = (const float*)d_in[14];
  const float* w2    = (const float*)d_in[15];
  const float* b2    = (const float*)d_in[16];
  const float* gmsa  = (const float*)d_in[17];
  const float* gmlp  = (const float*)d_in[18];
  float* out = (float*)d_out;

  char* w = (char*)d_ws;
  auto alloc = [&](size_t bytes) {
    char* p = w;
    w += (bytes + 255) & ~(size_t)255;
    return p;
  };
  u16* h1     = (u16*)alloc(4096UL * 1024 * 2);
  u16* wqkv_t = (u16*)alloc(3072UL * 1024 * 2);
  u16* wo_t   = (u16*)alloc(1024UL * 1024 * 2);
  u16* w1_t   = (u16*)alloc(4096UL * 1024 * 2);
  u16* w2_t   = (u16*)alloc(1024UL * 4096 * 2);
  float* bqkv = (float*)alloc(3072UL * 4);
  u16* qkv    = (u16*)alloc(4096UL * 3072 * 2);
  u16* q_r    = (u16*)alloc(65536UL * 64 * 2);
  u16* k_r    = (u16*)alloc(65536UL * 64 * 2);
  u16* v_t    = (u16*)alloc(65536UL * 64 * 2);
  u16* o_at   = (u16*)alloc(4096UL * 1024 * 2);
  u16* h2     = (u16*)alloc(4096UL * 1024 * 2);
  u16* g1     = (u16*)alloc(4096UL * 4096 * 2);

  // weights -> bf16, transposed to (N x K); qkv packed [wq; wk; wv]
  tcvt_k<<<dim3(32, 32), 256, 0, stream>>>(wq, wqkv_t, 1024, 1024);
  tcvt_k<<<dim3(32, 32), 256, 0, stream>>>(wk, wqkv_t + 1024 * 1024, 1024, 1024);
  tcvt_k<<<dim3(32, 32), 256, 0, stream>>>(wv, wqkv_t + 2048 * 1024, 1024, 1024);
  tcvt_k<<<dim3(32, 32), 256, 0, stream>>>(wo, wo_t, 1024, 1024);
  tcvt_k<<<dim3(32, 128), 256, 0, stream>>>(w1, w1_t, 1024, 4096);
  tcvt_k<<<dim3(128, 32), 256, 0, stream>>>(w2, w2_t, 4096, 1024);
  hipMemcpyAsync(bqkv,        bq, 1024 * sizeof(float), hipMemcpyDeviceToDevice, stream);
  hipMemcpyAsync(bqkv + 1024, bk, 1024 * sizeof(float), hipMemcpyDeviceToDevice, stream);
  hipMemcpyAsync(bqkv + 2048, bv, 1024 * sizeof(float), hipMemcpyDeviceToDevice, stream);

  // attention branch
  ln_k<<<4096, 256, 0, stream>>>(x, ln1_g, ln1_b, h1);
  gemm_bt<0><<<dim3(32, 24), 256, 0, stream>>>(h1, wqkv_t, bqkv, nullptr, nullptr, qkv, 4096, 3072, 1024);
  rope_k<<<dim3(8192, 2), 256, 0, stream>>>(qkv, q_r, k_r);
  vtrans_k<<<1024, 256, 0, stream>>>(qkv, v_t);
  attn_k<<<dim3(32, 32), 256, 0, stream>>>(q_r, k_r, v_t, o_at);
  // x1 = x + gate_msa * (o @ wo + bo)  -> written to d_out (fp32)
  gemm_bt<2><<<dim3(32, 8), 256, 0, stream>>>(o_at, wo_t, bo, x, gmsa, out, 4096, 1024, 1024);

  // MLP branch (accumulates into d_out)
  ln_k<<<4096, 256, 0, stream>>>(out, ln2_g, ln2_b, h2);
  gemm_bt<1><<<dim3(32, 32), 256, 0, stream>>>(h2, w1_t, b1, nullptr, nullptr, g1, 4096, 4096, 1024);
  gemm_bt<3><<<dim3(32, 8), 256, 0, stream>>>(g1, w2_t, b2, nullptr, gmlp, out, 4096, 1024, 4096);
}

// Round 2
// 515.748 us; speedup vs baseline: 1.0921x; 1.0921x over previous
//
#include <hip/hip_runtime.h>

typedef unsigned short u16;
typedef __attribute__((ext_vector_type(4))) float f32x4;
typedef __attribute__((ext_vector_type(8))) short bf16x8;

#define DEV static __device__ __forceinline__

DEV float bf2f(u16 u) { unsigned int i = ((unsigned int)u) << 16; return __builtin_bit_cast(float, i); }
DEV u16 f2bf(float f) {
  unsigned int x = __builtin_bit_cast(unsigned int, f);
  x += 0x7fffu + ((x >> 16) & 1u);
  return (u16)(x >> 16);
}

DEV void gload16(const u16* g, u16* l) {
  __builtin_amdgcn_global_load_lds(
      (const __attribute__((address_space(1))) unsigned int*)g,
      (__attribute__((address_space(3))) unsigned int*)l, 16, 0, 0);
}

// ---------------- LayerNorm: fp32 in -> bf16 out (D=1024, one block per row) ----------------
__global__ __launch_bounds__(256) void ln_k(const float* __restrict__ x,
                                            const float* __restrict__ g,
                                            const float* __restrict__ b,
                                            u16* __restrict__ out) {
  const int row = blockIdx.x;
  const int t = threadIdx.x;
  const float4 v = *(const float4*)(x + (size_t)row * 1024 + t * 4);
  float s = v.x + v.y + v.z + v.w;
  float q = v.x * v.x + v.y * v.y + v.z * v.z + v.w * v.w;
#pragma unroll
  for (int m = 1; m < 64; m <<= 1) { s += __shfl_xor(s, m); q += __shfl_xor(q, m); }
  __shared__ float ss[4], qs[4];
  if ((t & 63) == 0) { ss[t >> 6] = s; qs[t >> 6] = q; }
  __syncthreads();
  s = ss[0] + ss[1] + ss[2] + ss[3];
  q = qs[0] + qs[1] + qs[2] + qs[3];
  const float mean = s * (1.0f / 1024.0f);
  const float var = q * (1.0f / 1024.0f) - mean * mean;
  const float rs = rsqrtf(var + 1e-6f);
  const float4 gv = *(const float4*)(g + t * 4);
  const float4 bv = *(const float4*)(b + t * 4);
  ushort4 o;
  o.x = f2bf((v.x - mean) * rs * gv.x + bv.x);
  o.y = f2bf((v.y - mean) * rs * gv.y + bv.y);
  o.z = f2bf((v.z - mean) * rs * gv.z + bv.z);
  o.w = f2bf((v.w - mean) * rs * gv.w + bv.w);
  *(ushort4*)(out + (size_t)row * 1024 + t * 4) = o;
}

// ---------------- weight transpose + cvt: src (K x N) f32 -> dst (N x K) bf16 ----------------
__global__ __launch_bounds__(256) void tcvt_k(const float* __restrict__ src,
                                              u16* __restrict__ dst, int K, int N) {
  __shared__ u16 tl[32][33];
  const int k0 = blockIdx.x * 32, n0 = blockIdx.y * 32;
  const int c = threadIdx.x & 31, r0 = threadIdx.x >> 5;
#pragma unroll
  for (int p = 0; p < 4; p++) {
    const int r = p * 8 + r0;
    tl[r][c] = f2bf(src[(size_t)(k0 + r) * N + n0 + c]);
  }
  __syncthreads();
#pragma unroll
  for (int p = 0; p < 4; p++) {
    const int r = p * 8 + r0;
    dst[(size_t)(n0 + r) * K + k0 + c] = tl[c][r];
  }
}

// ---------------- GEMM: C(MxN) = A(MxK,bf16) @ Bt(NxK,bf16)^T, fused epilogues ----------------
// EPI 0: out bf16 = acc + bias
// EPI 1: out bf16 = gelu(acc + bias)
// EPI 2: out f32  = resid + gate[col]*(acc + bias)
// EPI 3: out f32 += gate[col]*(acc + bias)
template <int EPI>
__global__ __launch_bounds__(256) void gemm_bt(const u16* __restrict__ A,
                                               const u16* __restrict__ Bt,
                                               const float* __restrict__ bias,
                                               const float* __restrict__ resid,
                                               const float* __restrict__ gate,
                                               void* __restrict__ outv,
                                               int M, int N, int K) {
  __shared__ u16 lA[128 * 32];
  __shared__ u16 lB[128 * 32];
  const int tid = threadIdx.x;
  const int lane = tid & 63, wid = tid >> 6;
  const int l4 = lane >> 4, l15 = lane & 15;
  const int wr = wid >> 1, wc = wid & 1;
  const int mBase = blockIdx.x * 128;
  const int nBase = blockIdx.y * 128;

  f32x4 acc[4][4];
#pragma unroll
  for (int i = 0; i < 4; i++)
#pragma unroll
    for (int j = 0; j < 4; j++)
#pragma unroll
      for (int e = 0; e < 4; e++) acc[i][j][e] = 0.f;

  const int sRow = tid >> 2;
  const int sCol = (tid & 3) * 8;

  for (int k0 = 0; k0 < K; k0 += 32) {
#pragma unroll
    for (int r2 = 0; r2 < 2; r2++) {
      gload16(A + (size_t)(mBase + r2 * 64 + sRow) * K + k0 + sCol, lA + r2 * 2048 + wid * 512);
      gload16(Bt + (size_t)(nBase + r2 * 64 + sRow) * K + k0 + sCol, lB + r2 * 2048 + wid * 512);
    }
    __syncthreads();
    bf16x8 af[4], bf[4];
#pragma unroll
    for (int mi = 0; mi < 4; mi++)
      af[mi] = *(const bf16x8*)(lA + (wr * 64 + mi * 16 + l15) * 32 + l4 * 8);
#pragma unroll
    for (int ni = 0; ni < 4; ni++)
      bf[ni] = *(const bf16x8*)(lB + (wc * 64 + ni * 16 + l15) * 32 + l4 * 8);
#pragma unroll
    for (int mi = 0; mi < 4; mi++)
#pragma unroll
      for (int ni = 0; ni < 4; ni++)
        acc[mi][ni] = __builtin_amdgcn_mfma_f32_16x16x32_bf16(af[mi], bf[ni], acc[mi][ni], 0, 0, 0);
    __syncthreads();
  }

  u16* obf = (u16*)outv;
  float* of = (float*)outv;
#pragma unroll
  for (int mi = 0; mi < 4; mi++) {
#pragma unroll
    for (int ni = 0; ni < 4; ni++) {
      const int row0 = mBase + wr * 64 + mi * 16 + l4 * 4;
      const int col = nBase + wc * 64 + ni * 16 + l15;
      const float bb = bias[col];
#pragma unroll
      for (int r = 0; r < 4; r++) {
        const float v = acc[mi][ni][r] + bb;
        const size_t idx = (size_t)(row0 + r) * N + col;
        if (EPI == 0) {
          obf[idx] = f2bf(v);
        } else if (EPI == 1) {
          const float ge = 0.5f * v * (1.0f + erff(v * 0.70710678118654752f));
          obf[idx] = f2bf(ge);
        } else if (EPI == 2) {
          of[idx] = resid[idx] + gate[col] * v;
        } else {
          of[idx] = of[idx] + gate[col] * v;
        }
      }
    }
  }
}

// ---------------- RoPE + head-layout: qkv(4096x3072 bf16) -> q_r/k_r (B,H,L,hd) bf16 ----------------
// q additionally pre-scaled by 1/sqrt(hd) = 0.125 so attention uses raw dot products.
__global__ __launch_bounds__(256) void rope_k(const u16* __restrict__ qkv,
                                              u16* __restrict__ qr, u16* __restrict__ kr) {
  const int sel = blockIdx.y;  // 0 -> q, 1 -> k
  const int rid = blockIdx.x * 8 + (threadIdx.x >> 5);  // (b,h,t) row id, 0..65535
  const int i = threadIdx.x & 31;                       // pair index 0..31
  const int b = rid >> 15;
  const int h = (rid >> 11) & 15;
  const int t = rid & 2047;
  const u16* src = qkv + (size_t)(b * 2048 + t) * 3072 + sel * 1024 + h * 64 + 2 * i;
  const ushort2 uv = *(const ushort2*)src;
  const float x0 = bf2f(uv.x), x1 = bf2f(uv.y);
  const float inv = __expf(-(float)i * 0.28782313662425572f);  // ln(10000)/32
  float sn, cs;
  sincosf((float)t * inv, &sn, &cs);
  const float sc = sel ? 1.0f : 0.125f;
  ushort2 ov;
  ov.x = f2bf((x0 * cs - x1 * sn) * sc);
  ov.y = f2bf((x1 * cs + x0 * sn) * sc);
  *(ushort2*)((sel ? kr : qr) + (size_t)rid * 64 + 2 * i) = ov;
}

// ---------------- V layout: qkv cols 2048.. -> v_t (B,H,hd,L) bf16 (transposed) ----------------
__global__ __launch_bounds__(256) void vtrans_k(const u16* __restrict__ qkv, u16* __restrict__ vt) {
  __shared__ u16 tl[64][65];
  const int bh = blockIdx.x >> 5;
  const int t0 = (blockIdx.x & 31) * 64;
  const int b = bh >> 4, h = bh & 15;
  const int tid = threadIdx.x;
#pragma unroll
  for (int p = 0; p < 16; p++) {
    const int e = p * 256 + tid;
    const int tr = e >> 6, d = e & 63;
    tl[tr][d] = qkv[(size_t)(b * 2048 + t0 + tr) * 3072 + 2048 + h * 64 + d];
  }
  __syncthreads();
#pragma unroll
  for (int p = 0; p < 16; p++) {
    const int e = p * 256 + tid;
    const int dr = e >> 6, tc = e & 63;
    vt[(size_t)(bh * 64 + dr) * 2048 + t0 + tc] = tl[tc][dr];
  }
}

// ---------------- Flash attention, swapped-QK^T softmax ----------------
// q,k: (B,H,L,hd) bf16 (q pre-scaled); vt: (B,H,hd,L) bf16 ; o: (B,L,D) bf16
// Per wave: 16 q-rows, KVBLK=64.
// QK^T computed swapped: mfma(A=K, B=Q) -> S^T[kv][q]; lane(l4,l15) holds
// s[kt][r] = S^T[kv0+kt*16+l4*4+r][q=l15]. Row-softmax reduce = 15 in-lane ops
// + shfl_xor(16,32). P written to LDS (b64, XOR-swizzled), PV reads straight.
// Per-q scale factors cross domains via 16-float LDS broadcast.
__global__ __launch_bounds__(256) void attn_k(const u16* __restrict__ q,
                                              const u16* __restrict__ k,
                                              const u16* __restrict__ vt,
                                              u16* __restrict__ o) {
  const int bh = blockIdx.y;
  const int wid = threadIdx.x >> 6, lane = threadIdx.x & 63;
  const int l4 = lane >> 4, l15 = lane & 15;
  const int qrow0 = blockIdx.x * 64 + wid * 16;
  const size_t qoff = ((size_t)bh * 2048 + qrow0) * 64;
  const bf16x8 qf0 = *(const bf16x8*)(q + qoff + l15 * 64 + l4 * 8);
  const bf16x8 qf1 = *(const bf16x8*)(q + qoff + l15 * 64 + 32 + l4 * 8);

  float m = -1e30f, lsum = 0.f;
  f32x4 oacc[4];
#pragma unroll
  for (int ni = 0; ni < 4; ni++)
#pragma unroll
    for (int e = 0; e < 4; e++) oacc[ni][e] = 0.f;

  __shared__ u16 plds[4][16 * 64];  // per wave: 16 rows x 128 B
  __shared__ float alds[4][16];
  char* P = (char*)plds[wid];
  float* AL = alds[wid];
  char* prow = P + l15 * 128;
  const int swz = (l15 & 7) << 4;  // byte XOR swizzle, multiple of 16
  const u16* kbase = k + (size_t)bh * 2048 * 64;
  const u16* vbase = vt + (size_t)bh * 64 * 2048;

  for (int kv = 0; kv < 2048; kv += 64) {
    f32x4 s[4];
#pragma unroll
    for (int kt = 0; kt < 4; kt++) {
      const u16* kb = kbase + (size_t)(kv + kt * 16 + l15) * 64 + l4 * 8;
      const bf16x8 kf0 = *(const bf16x8*)kb;
      const bf16x8 kf1 = *(const bf16x8*)(kb + 32);
      f32x4 z = {0.f, 0.f, 0.f, 0.f};
      z = __builtin_amdgcn_mfma_f32_16x16x32_bf16(kf0, qf0, z, 0, 0, 0);
      s[kt] = __builtin_amdgcn_mfma_f32_16x16x32_bf16(kf1, qf1, z, 0, 0, 0);
    }
    // row max (per q = l15)
    float pmax = s[0][0];
#pragma unroll
    for (int kt = 0; kt < 4; kt++)
#pragma unroll
      for (int r = 0; r < 4; r++) pmax = fmaxf(pmax, s[kt][r]);
    pmax = fmaxf(pmax, __shfl_xor(pmax, 16));
    pmax = fmaxf(pmax, __shfl_xor(pmax, 32));
    const bool need = !__all(pmax <= m + 8.0f);  // defer-max (T13)
    float al = 1.0f;
    if (need) {
      const float mn = fmaxf(m, pmax);
      al = __expf(m - mn);
      m = mn;
      if (l4 == 0) AL[l15] = al;
    }
    float p[4][4];
    float ps = 0.f;
#pragma unroll
    for (int kt = 0; kt < 4; kt++)
#pragma unroll
      for (int r = 0; r < 4; r++) {
        p[kt][r] = __expf(s[kt][r] - m);
        ps += p[kt][r];
      }
    ps += __shfl_xor(ps, 16);
    ps += __shfl_xor(ps, 32);
    lsum = lsum * al + ps;
    // P -> LDS: P[q=l15][kv0 + kt*16 + l4*4 .. +3], b64 writes, XOR-swizzled
#pragma unroll
    for (int kt = 0; kt < 4; kt++) {
      uint2 wv;
      wv.x = (unsigned)f2bf(p[kt][0]) | ((unsigned)f2bf(p[kt][1]) << 16);
      wv.y = (unsigned)f2bf(p[kt][2]) | ((unsigned)f2bf(p[kt][3]) << 16);
      *(uint2*)(prow + ((kt * 32 + l4 * 8) ^ swz)) = wv;
    }
    asm volatile("s_waitcnt lgkmcnt(0)" ::: "memory");
    const bf16x8 pa0 = *(const bf16x8*)(prow + ((l4 * 16) ^ swz));
    const bf16x8 pa1 = *(const bf16x8*)(prow + ((64 + l4 * 16) ^ swz));
    if (need) {
      const f32x4 alv = *(const f32x4*)((const char*)AL + l4 * 16);  // al for q = l4*4+r
#pragma unroll
      for (int ni = 0; ni < 4; ni++) oacc[ni] *= alv;
    }
#pragma unroll
    for (int ni = 0; ni < 4; ni++) {
      const u16* vb = vbase + (size_t)(ni * 16 + l15) * 2048 + kv + l4 * 8;
      const bf16x8 v0 = *(const bf16x8*)vb;
      const bf16x8 v1 = *(const bf16x8*)(vb + 32);
      oacc[ni] = __builtin_amdgcn_mfma_f32_16x16x32_bf16(pa0, v0, oacc[ni], 0, 0, 0);
      oacc[ni] = __builtin_amdgcn_mfma_f32_16x16x32_bf16(pa1, v1, oacc[ni], 0, 0, 0);
    }
  }
  if (l4 == 0) AL[l15] = 1.0f / lsum;
  asm volatile("s_waitcnt lgkmcnt(0)" ::: "memory");
  const f32x4 invv = *(const f32x4*)((const char*)AL + l4 * 16);
  const int b = bh >> 4, h = bh & 15;
#pragma unroll
  for (int r = 0; r < 4; r++) {
    const size_t row = (size_t)b * 2048 + qrow0 + l4 * 4 + r;
#pragma unroll
    for (int ni = 0; ni < 4; ni++)
      o[row * 1024 + h * 64 + ni * 16 + l15] = f2bf(oacc[ni][r] * invv[r]);
  }
}

extern "C" void kernel_launch(void* const* d_in, const int* in_sizes, int n_in,
                              void* d_out, int out_size, void* d_ws, size_t ws_size,
                              hipStream_t stream) {
  (void)in_sizes; (void)n_in; (void)out_size; (void)ws_size;
  const float* x     = (const float*)d_in[0];
  const float* ln1_g = (const float*)d_in[1];
  const float* ln1_b = (const float*)d_in[2];
  const float* wq    = (const float*)d_in[3];
  const float* bq    = (const float*)d_in[4];
  const float* wk    = (const float*)d_in[5];
  const float* bk    = (const float*)d_in[6];
  const float* wv    = (const float*)d_in[7];
  const float* bv    = (const float*)d_in[8];
  const float* wo    = (const float*)d_in[9];
  const float* bo    = (const float*)d_in[10];
  const float* ln2_g = (const float*)d_in[11];
  const float* ln2_b = (const float*)d_in[12];
  const float* w1    = (const float*)d_in[13];
  const float* b1    = (const float*)d_in[14];
  const float* w2    = (const float*)d_in[15];
  const float* b2    = (const float*)d_in[16];
  const float* gmsa  = (const float*)d_in[17];
  const float* gmlp  = (const float*)d_in[18];
  float* out = (float*)d_out;

  char* w = (char*)d_ws;
  auto alloc = [&](size_t bytes) {
    char* p = w;
    w += (bytes + 255) & ~(size_t)255;
    return p;
  };
  u16* h1     = (u16*)alloc(4096UL * 1024 * 2);
  u16* wqkv_t = (u16*)alloc(3072UL * 1024 * 2);
  u16* wo_t   = (u16*)alloc(1024UL * 1024 * 2);
  u16* w1_t   = (u16*)alloc(4096UL * 1024 * 2);
  u16* w2_t   = (u16*)alloc(1024UL * 4096 * 2);
  float* bqkv = (float*)alloc(3072UL * 4);
  u16* qkv    = (u16*)alloc(4096UL * 3072 * 2);
  u16* q_r    = (u16*)alloc(65536UL * 64 * 2);
  u16* k_r    = (u16*)alloc(65536UL * 64 * 2);
  u16* v_t    = (u16*)alloc(65536UL * 64 * 2);
  u16* o_at   = (u16*)alloc(4096UL * 1024 * 2);
  u16* h2     = (u16*)alloc(4096UL * 1024 * 2);
  u16* g1     = (u16*)alloc(4096UL * 4096 * 2);

  // weights -> bf16, transposed to (N x K); qkv packed [wq; wk; wv]
  tcvt_k<<<dim3(32, 32), 256, 0, stream>>>(wq, wqkv_t, 1024, 1024);
  tcvt_k<<<dim3(32, 32), 256, 0, stream>>>(wk, wqkv_t + 1024 * 1024, 1024, 1024);
  tcvt_k<<<dim3(32, 32), 256, 0, stream>>>(wv, wqkv_t + 2048 * 1024, 1024, 1024);
  tcvt_k<<<dim3(32, 32), 256, 0, stream>>>(wo, wo_t, 1024, 1024);
  tcvt_k<<<dim3(32, 128), 256, 0, stream>>>(w1, w1_t, 1024, 4096);
  tcvt_k<<<dim3(128, 32), 256, 0, stream>>>(w2, w2_t, 4096, 1024);
  hipMemcpyAsync(bqkv,        bq, 1024 * sizeof(float), hipMemcpyDeviceToDevice, stream);
  hipMemcpyAsync(bqkv + 1024, bk, 1024 * sizeof(float), hipMemcpyDeviceToDevice, stream);
  hipMemcpyAsync(bqkv + 2048, bv, 1024 * sizeof(float), hipMemcpyDeviceToDevice, stream);

  // attention branch
  ln_k<<<4096, 256, 0, stream>>>(x, ln1_g, ln1_b, h1);
  gemm_bt<0><<<dim3(32, 24), 256, 0, stream>>>(h1, wqkv_t, bqkv, nullptr, nullptr, qkv, 4096, 3072, 1024);
  rope_k<<<dim3(8192, 2), 256, 0, stream>>>(qkv, q_r, k_r);
  vtrans_k<<<1024, 256, 0, stream>>>(qkv, v_t);
  attn_k<<<dim3(32, 32), 256, 0, stream>>>(q_r, k_r, v_t, o_at);
  // x1 = x + gate_msa * (o @ wo + bo)  -> written to d_out (fp32)
  gemm_bt<2><<<dim3(32, 8), 256, 0, stream>>>(o_at, wo_t, bo, x, gmsa, out, 4096, 1024, 1024);

  // MLP branch (accumulates into d_out)
  ln_k<<<4096, 256, 0, stream>>>(out, ln2_g, ln2_b, h2);
  gemm_bt<1><<<dim3(32, 32), 256, 0, stream>>>(h2, w1_t, b1, nullptr, nullptr, g1, 4096, 4096, 1024);
  gemm_bt<3><<<dim3(32, 8), 256, 0, stream>>>(g1, w2_t, b2, nullptr, gmlp, out, 4096, 1024, 4096);
}

// Round 3
// 363.876 us; speedup vs baseline: 1.5479x; 1.4174x over previous
//
#include <hip/hip_runtime.h>

typedef unsigned short u16;
typedef __attribute__((ext_vector_type(4))) float f32x4;
typedef __attribute__((ext_vector_type(8))) short bf16x8;

#define DEV static __device__ __forceinline__

DEV float bf2f(u16 u) { unsigned int i = ((unsigned int)u) << 16; return __builtin_bit_cast(float, i); }
DEV u16 f2bf(float f) {
  unsigned int x = __builtin_bit_cast(unsigned int, f);
  x += 0x7fffu + ((x >> 16) & 1u);
  return (u16)(x >> 16);
}

DEV void gload16(const u16* g, u16* l) {
  __builtin_amdgcn_global_load_lds(
      (const __attribute__((address_space(1))) unsigned int*)g,
      (__attribute__((address_space(3))) unsigned int*)l, 16, 0, 0);
}

// ---------------- LayerNorm: fp32 in -> bf16 out (D=1024, one block per row) ----------------
__global__ __launch_bounds__(256) void ln_k(const float* __restrict__ x,
                                            const float* __restrict__ g,
                                            const float* __restrict__ b,
                                            u16* __restrict__ out) {
  const int row = blockIdx.x;
  const int t = threadIdx.x;
  const float4 v = *(const float4*)(x + (size_t)row * 1024 + t * 4);
  float s = v.x + v.y + v.z + v.w;
  float q = v.x * v.x + v.y * v.y + v.z * v.z + v.w * v.w;
#pragma unroll
  for (int m = 1; m < 64; m <<= 1) { s += __shfl_xor(s, m); q += __shfl_xor(q, m); }
  __shared__ float ss[4], qs[4];
  if ((t & 63) == 0) { ss[t >> 6] = s; qs[t >> 6] = q; }
  __syncthreads();
  s = ss[0] + ss[1] + ss[2] + ss[3];
  q = qs[0] + qs[1] + qs[2] + qs[3];
  const float mean = s * (1.0f / 1024.0f);
  const float var = q * (1.0f / 1024.0f) - mean * mean;
  const float rs = rsqrtf(var + 1e-6f);
  const float4 gv = *(const float4*)(g + t * 4);
  const float4 bv = *(const float4*)(b + t * 4);
  ushort4 o;
  o.x = f2bf((v.x - mean) * rs * gv.x + bv.x);
  o.y = f2bf((v.y - mean) * rs * gv.y + bv.y);
  o.z = f2bf((v.z - mean) * rs * gv.z + bv.z);
  o.w = f2bf((v.w - mean) * rs * gv.w + bv.w);
  *(ushort4*)(out + (size_t)row * 1024 + t * 4) = o;
}

// ---------------- weight transpose + cvt: src (K x N) f32 -> dst (N x K) bf16 ----------------
__global__ __launch_bounds__(256) void tcvt_k(const float* __restrict__ src,
                                              u16* __restrict__ dst, int K, int N) {
  __shared__ u16 tl[32][33];
  const int k0 = blockIdx.x * 32, n0 = blockIdx.y * 32;
  const int c = threadIdx.x & 31, r0 = threadIdx.x >> 5;
#pragma unroll
  for (int p = 0; p < 4; p++) {
    const int r = p * 8 + r0;
    tl[r][c] = f2bf(src[(size_t)(k0 + r) * N + n0 + c]);
  }
  __syncthreads();
#pragma unroll
  for (int p = 0; p < 4; p++) {
    const int r = p * 8 + r0;
    dst[(size_t)(n0 + r) * K + k0 + c] = tl[c][r];
  }
}

// ---------------- GEMM: C(MxN) = A(MxK,bf16) @ Bt(NxK,bf16)^T, fused epilogues ----------------
// EPI 0: out bf16 = acc + bias
// EPI 1: out bf16 = gelu(acc + bias)
// EPI 2: out f32  = resid + gate[col]*(acc + bias)
// EPI 3: out f32 += gate[col]*(acc + bias)
template <int EPI>
__global__ __launch_bounds__(256) void gemm_bt(const u16* __restrict__ A,
                                               const u16* __restrict__ Bt,
                                               const float* __restrict__ bias,
                                               const float* __restrict__ resid,
                                               const float* __restrict__ gate,
                                               void* __restrict__ outv,
                                               int M, int N, int K) {
  __shared__ u16 lA[128 * 32];
  __shared__ u16 lB[128 * 32];
  const int tid = threadIdx.x;
  const int lane = tid & 63, wid = tid >> 6;
  const int l4 = lane >> 4, l15 = lane & 15;
  const int wr = wid >> 1, wc = wid & 1;
  const int mBase = blockIdx.x * 128;
  const int nBase = blockIdx.y * 128;

  f32x4 acc[4][4];
#pragma unroll
  for (int i = 0; i < 4; i++)
#pragma unroll
    for (int j = 0; j < 4; j++)
#pragma unroll
      for (int e = 0; e < 4; e++) acc[i][j][e] = 0.f;

  const int sRow = tid >> 2;
  const int sCol = (tid & 3) * 8;

  for (int k0 = 0; k0 < K; k0 += 32) {
#pragma unroll
    for (int r2 = 0; r2 < 2; r2++) {
      gload16(A + (size_t)(mBase + r2 * 64 + sRow) * K + k0 + sCol, lA + r2 * 2048 + wid * 512);
      gload16(Bt + (size_t)(nBase + r2 * 64 + sRow) * K + k0 + sCol, lB + r2 * 2048 + wid * 512);
    }
    __syncthreads();
    bf16x8 af[4], bf[4];
#pragma unroll
    for (int mi = 0; mi < 4; mi++)
      af[mi] = *(const bf16x8*)(lA + (wr * 64 + mi * 16 + l15) * 32 + l4 * 8);
#pragma unroll
    for (int ni = 0; ni < 4; ni++)
      bf[ni] = *(const bf16x8*)(lB + (wc * 64 + ni * 16 + l15) * 32 + l4 * 8);
#pragma unroll
    for (int mi = 0; mi < 4; mi++)
#pragma unroll
      for (int ni = 0; ni < 4; ni++)
        acc[mi][ni] = __builtin_amdgcn_mfma_f32_16x16x32_bf16(af[mi], bf[ni], acc[mi][ni], 0, 0, 0);
    __syncthreads();
  }

  u16* obf = (u16*)outv;
  float* of = (float*)outv;
#pragma unroll
  for (int mi = 0; mi < 4; mi++) {
#pragma unroll
    for (int ni = 0; ni < 4; ni++) {
      const int row0 = mBase + wr * 64 + mi * 16 + l4 * 4;
      const int col = nBase + wc * 64 + ni * 16 + l15;
      const float bb = bias[col];
#pragma unroll
      for (int r = 0; r < 4; r++) {
        const float v = acc[mi][ni][r] + bb;
        const size_t idx = (size_t)(row0 + r) * N + col;
        if (EPI == 0) {
          obf[idx] = f2bf(v);
        } else if (EPI == 1) {
          const float ge = 0.5f * v * (1.0f + erff(v * 0.70710678118654752f));
          obf[idx] = f2bf(ge);
        } else if (EPI == 2) {
          of[idx] = resid[idx] + gate[col] * v;
        } else {
          of[idx] = of[idx] + gate[col] * v;
        }
      }
    }
  }
}

// ---------------- RoPE + head-layout: qkv(4096x3072 bf16) -> q_r/k_r (B,H,L,hd) bf16 ----------------
// q additionally pre-scaled by 1/sqrt(hd) = 0.125 so attention uses raw dot products.
__global__ __launch_bounds__(256) void rope_k(const u16* __restrict__ qkv,
                                              u16* __restrict__ qr, u16* __restrict__ kr) {
  const int sel = blockIdx.y;  // 0 -> q, 1 -> k
  const int rid = blockIdx.x * 8 + (threadIdx.x >> 5);  // (b,h,t) row id, 0..65535
  const int i = threadIdx.x & 31;                       // pair index 0..31
  const int b = rid >> 15;
  const int h = (rid >> 11) & 15;
  const int t = rid & 2047;
  const u16* src = qkv + (size_t)(b * 2048 + t) * 3072 + sel * 1024 + h * 64 + 2 * i;
  const ushort2 uv = *(const ushort2*)src;
  const float x0 = bf2f(uv.x), x1 = bf2f(uv.y);
  const float inv = __expf(-(float)i * 0.28782313662425572f);  // ln(10000)/32
  float sn, cs;
  sincosf((float)t * inv, &sn, &cs);
  const float sc = sel ? 1.0f : 0.125f;
  ushort2 ov;
  ov.x = f2bf((x0 * cs - x1 * sn) * sc);
  ov.y = f2bf((x1 * cs + x0 * sn) * sc);
  *(ushort2*)((sel ? kr : qr) + (size_t)rid * 64 + 2 * i) = ov;
}

// ---------------- V layout: qkv cols 2048.. -> v_t (B,H,hd,L) bf16 (transposed) ----------------
__global__ __launch_bounds__(256) void vtrans_k(const u16* __restrict__ qkv, u16* __restrict__ vt) {
  __shared__ u16 tl[64][65];
  const int bh = blockIdx.x >> 5;
  const int t0 = (blockIdx.x & 31) * 64;
  const int b = bh >> 4, h = bh & 15;
  const int tid = threadIdx.x;
#pragma unroll
  for (int p = 0; p < 16; p++) {
    const int e = p * 256 + tid;
    const int tr = e >> 6, d = e & 63;
    tl[tr][d] = qkv[(size_t)(b * 2048 + t0 + tr) * 3072 + 2048 + h * 64 + d];
  }
  __syncthreads();
#pragma unroll
  for (int p = 0; p < 16; p++) {
    const int e = p * 256 + tid;
    const int dr = e >> 6, tc = e & 63;
    vt[(size_t)(bh * 64 + dr) * 2048 + t0 + tc] = tl[tc][dr];
  }
}

// ---------------- Flash attention: LDS-staged K/V (dbuf), 4 waves x 32 q-rows ----------------
// q,k: (B,H,L,hd) bf16 (q pre-scaled); vt: (B,H,hd,L) bf16 ; o: (B,L,D) bf16
// Per iter: stage next K/V tile (global_load_lds, pre-swizzled source -> linear LDS ->
// XOR-swizzled reads, 2-way=free); swapped QK^T (S^T), in-lane softmax with defer-max;
// P via per-wave LDS; PV from LDS V^T tile. One barrier per iter (drains vmcnt).
__global__ __launch_bounds__(256) void attn_k(const u16* __restrict__ q,
                                              const u16* __restrict__ k,
                                              const u16* __restrict__ vt,
                                              u16* __restrict__ o) {
  const int bh = blockIdx.y;
  const int tid = threadIdx.x;
  const int wid = tid >> 6, lane = tid & 63;
  const int l4 = lane >> 4, l15 = lane & 15;
  const int qrow0 = blockIdx.x * 128 + wid * 32;

  __shared__ __align__(16) u16 kls[2][4096];   // K tile [64 kv][64 d], row-XOR-swizzled
  __shared__ __align__(16) u16 vls[2][4096];   // V^T tile [64 d][64 kv], row-XOR-swizzled
  __shared__ __align__(16) u16 pls[4][2048];   // per-wave P [32 q][64 kv], row-XOR-swizzled
  __shared__ __align__(16) float alds[4][32];

  // Q fragments: 2 q-sets x 2 d-halves
  const size_t qoff = ((size_t)bh * 2048 + qrow0) * 64;
  bf16x8 qf[2][2];
#pragma unroll
  for (int g = 0; g < 2; g++) {
    qf[g][0] = *(const bf16x8*)(q + qoff + (size_t)(g * 16 + l15) * 64 + l4 * 8);
    qf[g][1] = *(const bf16x8*)(q + qoff + (size_t)(g * 16 + l15) * 64 + 32 + l4 * 8);
  }

  float m0 = -1e30f, m1 = -1e30f, ls0 = 0.f, ls1 = 0.f;
  f32x4 oacc[2][4];
#pragma unroll
  for (int g = 0; g < 2; g++)
#pragma unroll
    for (int ni = 0; ni < 4; ni++)
#pragma unroll
      for (int e = 0; e < 4; e++) oacc[g][ni][e] = 0.f;

  const char* kg = (const char*)(k + (size_t)bh * 2048 * 64);   // K rows: 128 B
  const char* vg = (const char*)(vt + (size_t)bh * 64 * 2048);  // V^T rows: 4096 B
  // staging slots: s = pass*256 + tid ; row = s>>3 ; source col pre-swizzled
  const int sA = tid, sB = 256 + tid;
  const int rA = sA >> 3, cA = ((sA & 7) ^ (rA & 7)) << 4;
  const int rB = sB >> 3, cB = ((sB & 7) ^ (rB & 7)) << 4;
  u16* kd0 = &kls[0][(size_t)(wid * 64) * 8];
  u16* kd1 = &kls[0][(size_t)(256 + wid * 64) * 8];
  u16* vd0 = &vls[0][(size_t)(wid * 64) * 8];
  u16* vd1 = &vls[0][(size_t)(256 + wid * 64) * 8];

#define STAGE(bufi, kv0)                                                            \
  {                                                                                 \
    const int _o = (bufi)*4096;                                                     \
    gload16((const u16*)(kg + (size_t)((kv0) + rA) * 128 + cA), kd0 + _o);          \
    gload16((const u16*)(kg + (size_t)((kv0) + rB) * 128 + cB), kd1 + _o);          \
    gload16((const u16*)(vg + (size_t)rA * 4096 + (kv0)*2 + cA), vd0 + _o);         \
    gload16((const u16*)(vg + (size_t)rB * 4096 + (kv0)*2 + cB), vd1 + _o);         \
  }

  STAGE(0, 0);
  __syncthreads();

  char* P = (char*)pls[wid];
  float* AL = alds[wid];
  char* prow0 = P + l15 * 128;
  char* prow1 = P + (16 + l15) * 128;
  const int psw = (l15 & 7) << 4;

  int buf = 0;
  for (int it = 0; it < 32; ++it) {
    if (it < 31) STAGE(buf ^ 1, (it + 1) * 64);
    const char* K = (const char*)kls[buf];
    const char* V = (const char*)vls[buf];

    // ---- QK^T (swapped): s[g][kt][r] = S^T[kv=kt*16+l4*4+r][q=g*16+l15]
    f32x4 s0[4], s1[4];
#pragma unroll
    for (int kt = 0; kt < 4; kt++) {
      const int row = kt * 16 + l15;
      const int sw = (row & 7) << 4;
      const char* kr = K + row * 128;
      const bf16x8 kf0 = *(const bf16x8*)(kr + ((l4 * 16) ^ sw));
      const bf16x8 kf1 = *(const bf16x8*)(kr + ((64 + l4 * 16) ^ sw));
      f32x4 z0 = {0.f, 0.f, 0.f, 0.f}, z1 = {0.f, 0.f, 0.f, 0.f};
      z0 = __builtin_amdgcn_mfma_f32_16x16x32_bf16(kf0, qf[0][0], z0, 0, 0, 0);
      s0[kt] = __builtin_amdgcn_mfma_f32_16x16x32_bf16(kf1, qf[0][1], z0, 0, 0, 0);
      z1 = __builtin_amdgcn_mfma_f32_16x16x32_bf16(kf0, qf[1][0], z1, 0, 0, 0);
      s1[kt] = __builtin_amdgcn_mfma_f32_16x16x32_bf16(kf1, qf[1][1], z1, 0, 0, 0);
    }

    // ---- softmax (per q = l15 / 16+l15)
    float pm0 = s0[0][0], pm1 = s1[0][0];
#pragma unroll
    for (int kt = 0; kt < 4; kt++)
#pragma unroll
      for (int r = 0; r < 4; r++) {
        pm0 = fmaxf(pm0, s0[kt][r]);
        pm1 = fmaxf(pm1, s1[kt][r]);
      }
    pm0 = fmaxf(pm0, __shfl_xor(pm0, 16));
    pm0 = fmaxf(pm0, __shfl_xor(pm0, 32));
    pm1 = fmaxf(pm1, __shfl_xor(pm1, 16));
    pm1 = fmaxf(pm1, __shfl_xor(pm1, 32));
    const bool need = !__all((pm0 <= m0 + 8.0f) && (pm1 <= m1 + 8.0f));  // defer-max
    float al0 = 1.0f, al1 = 1.0f;
    if (need) {
      const float mn0 = fmaxf(m0, pm0), mn1 = fmaxf(m1, pm1);
      al0 = __expf(m0 - mn0); al1 = __expf(m1 - mn1);
      m0 = mn0; m1 = mn1;
      if (l4 == 0) { AL[l15] = al0; AL[16 + l15] = al1; }
    }
    float ps0 = 0.f, ps1 = 0.f;
#pragma unroll
    for (int kt = 0; kt < 4; kt++)
#pragma unroll
      for (int r = 0; r < 4; r++) {
        s0[kt][r] = __expf(s0[kt][r] - m0); ps0 += s0[kt][r];
        s1[kt][r] = __expf(s1[kt][r] - m1); ps1 += s1[kt][r];
      }
    ps0 += __shfl_xor(ps0, 16); ps0 += __shfl_xor(ps0, 32);
    ps1 += __shfl_xor(ps1, 16); ps1 += __shfl_xor(ps1, 32);
    ls0 = ls0 * al0 + ps0;
    ls1 = ls1 * al1 + ps1;

    // ---- P -> LDS (b64 writes, XOR-swizzled rows)
#pragma unroll
    for (int kt = 0; kt < 4; kt++) {
      uint2 w0, w1;
      w0.x = (unsigned)f2bf(s0[kt][0]) | ((unsigned)f2bf(s0[kt][1]) << 16);
      w0.y = (unsigned)f2bf(s0[kt][2]) | ((unsigned)f2bf(s0[kt][3]) << 16);
      w1.x = (unsigned)f2bf(s1[kt][0]) | ((unsigned)f2bf(s1[kt][1]) << 16);
      w1.y = (unsigned)f2bf(s1[kt][2]) | ((unsigned)f2bf(s1[kt][3]) << 16);
      *(uint2*)(prow0 + ((kt * 32 + l4 * 8) ^ psw)) = w0;
      *(uint2*)(prow1 + ((kt * 32 + l4 * 8) ^ psw)) = w1;
    }
    asm volatile("s_waitcnt lgkmcnt(0)" ::: "memory");
    const bf16x8 pa00 = *(const bf16x8*)(prow0 + ((l4 * 16) ^ psw));
    const bf16x8 pa01 = *(const bf16x8*)(prow0 + ((64 + l4 * 16) ^ psw));
    const bf16x8 pa10 = *(const bf16x8*)(prow1 + ((l4 * 16) ^ psw));
    const bf16x8 pa11 = *(const bf16x8*)(prow1 + ((64 + l4 * 16) ^ psw));
    if (need) {
      const f32x4 a0 = *(const f32x4*)((const char*)AL + l4 * 16);
      const f32x4 a1 = *(const f32x4*)((const char*)AL + 64 + l4 * 16);
#pragma unroll
      for (int ni = 0; ni < 4; ni++) { oacc[0][ni] *= a0; oacc[1][ni] *= a1; }
    }

    // ---- PV from LDS V^T tile
#pragma unroll
    for (int ni = 0; ni < 4; ni++) {
      const int vrow = ni * 16 + l15;
      const int vsw = (vrow & 7) << 4;
      const char* vr = V + vrow * 128;
      const bf16x8 v0 = *(const bf16x8*)(vr + ((l4 * 16) ^ vsw));
      const bf16x8 v1 = *(const bf16x8*)(vr + ((64 + l4 * 16) ^ vsw));
      oacc[0][ni] = __builtin_amdgcn_mfma_f32_16x16x32_bf16(pa00, v0, oacc[0][ni], 0, 0, 0);
      oacc[0][ni] = __builtin_amdgcn_mfma_f32_16x16x32_bf16(pa01, v1, oacc[0][ni], 0, 0, 0);
      oacc[1][ni] = __builtin_amdgcn_mfma_f32_16x16x32_bf16(pa10, v0, oacc[1][ni], 0, 0, 0);
      oacc[1][ni] = __builtin_amdgcn_mfma_f32_16x16x32_bf16(pa11, v1, oacc[1][ni], 0, 0, 0);
    }
    __syncthreads();  // drains vmcnt(0): staged tile ready; old buf free
    buf ^= 1;
  }
#undef STAGE

  if (l4 == 0) { AL[l15] = 1.0f / ls0; AL[16 + l15] = 1.0f / ls1; }
  asm volatile("s_waitcnt lgkmcnt(0)" ::: "memory");
  const f32x4 iv0 = *(const f32x4*)((const char*)AL + l4 * 16);
  const f32x4 iv1 = *(const f32x4*)((const char*)AL + 64 + l4 * 16);
  const int b = bh >> 4, h = bh & 15;
#pragma unroll
  for (int g = 0; g < 2; g++) {
#pragma unroll
    for (int r = 0; r < 4; r++) {
      const size_t row = (size_t)b * 2048 + qrow0 + g * 16 + l4 * 4 + r;
      const float iv = g ? iv1[r] : iv0[r];
#pragma unroll
      for (int ni = 0; ni < 4; ni++)
        o[row * 1024 + h * 64 + ni * 16 + l15] = f2bf(oacc[g][ni][r] * iv);
    }
  }
}

extern "C" void kernel_launch(void* const* d_in, const int* in_sizes, int n_in,
                              void* d_out, int out_size, void* d_ws, size_t ws_size,
                              hipStream_t stream) {
  (void)in_sizes; (void)n_in; (void)out_size; (void)ws_size;
  const float* x     = (const float*)d_in[0];
  const float* ln1_g = (const float*)d_in[1];
  const float* ln1_b = (const float*)d_in[2];
  const float* wq    = (const float*)d_in[3];
  const float* bq    = (const float*)d_in[4];
  const float* wk    = (const float*)d_in[5];
  const float* bk    = (const float*)d_in[6];
  const float* wv    = (const float*)d_in[7];
  const float* bv    = (const float*)d_in[8];
  const float* wo    = (const float*)d_in[9];
  const float* bo    = (const float*)d_in[10];
  const float* ln2_g = (const float*)d_in[11];
  const float* ln2_b = (const float*)d_in[12];
  const float* w1    = (const float*)d_in[13];
  const float* b1    = (const float*)d_in[14];
  const float* w2    = (const float*)d_in[15];
  const float* b2    = (const float*)d_in[16];
  const float* gmsa  = (const float*)d_in[17];
  const float* gmlp  = (const float*)d_in[18];
  float* out = (float*)d_out;

  char* w = (char*)d_ws;
  auto alloc = [&](size_t bytes) {
    char* p = w;
    w += (bytes + 255) & ~(size_t)255;
    return p;
  };
  u16* h1     = (u16*)alloc(4096UL * 1024 * 2);
  u16* wqkv_t = (u16*)alloc(3072UL * 1024 * 2);
  u16* wo_t   = (u16*)alloc(1024UL * 1024 * 2);
  u16* w1_t   = (u16*)alloc(4096UL * 1024 * 2);
  u16* w2_t   = (u16*)alloc(1024UL * 4096 * 2);
  float* bqkv = (float*)alloc(3072UL * 4);
  u16* qkv    = (u16*)alloc(4096UL * 3072 * 2);
  u16* q_r    = (u16*)alloc(65536UL * 64 * 2);
  u16* k_r    = (u16*)alloc(65536UL * 64 * 2);
  u16* v_t    = (u16*)alloc(65536UL * 64 * 2);
  u16* o_at   = (u16*)alloc(4096UL * 1024 * 2);
  u16* h2     = (u16*)alloc(4096UL * 1024 * 2);
  u16* g1     = (u16*)alloc(4096UL * 4096 * 2);

  // weights -> bf16, transposed to (N x K); qkv packed [wq; wk; wv]
  tcvt_k<<<dim3(32, 32), 256, 0, stream>>>(wq, wqkv_t, 1024, 1024);
  tcvt_k<<<dim3(32, 32), 256, 0, stream>>>(wk, wqkv_t + 1024 * 1024, 1024, 1024);
  tcvt_k<<<dim3(32, 32), 256, 0, stream>>>(wv, wqkv_t + 2048 * 1024, 1024, 1024);
  tcvt_k<<<dim3(32, 32), 256, 0, stream>>>(wo, wo_t, 1024, 1024);
  tcvt_k<<<dim3(32, 128), 256, 0, stream>>>(w1, w1_t, 1024, 4096);
  tcvt_k<<<dim3(128, 32), 256, 0, stream>>>(w2, w2_t, 4096, 1024);
  hipMemcpyAsync(bqkv,        bq, 1024 * sizeof(float), hipMemcpyDeviceToDevice, stream);
  hipMemcpyAsync(bqkv + 1024, bk, 1024 * sizeof(float), hipMemcpyDeviceToDevice, stream);
  hipMemcpyAsync(bqkv + 2048, bv, 1024 * sizeof(float), hipMemcpyDeviceToDevice, stream);

  // attention branch
  ln_k<<<4096, 256, 0, stream>>>(x, ln1_g, ln1_b, h1);
  gemm_bt<0><<<dim3(32, 24), 256, 0, stream>>>(h1, wqkv_t, bqkv, nullptr, nullptr, qkv, 4096, 3072, 1024);
  rope_k<<<dim3(8192, 2), 256, 0, stream>>>(qkv, q_r, k_r);
  vtrans_k<<<1024, 256, 0, stream>>>(qkv, v_t);
  attn_k<<<dim3(16, 32), 256, 0, stream>>>(q_r, k_r, v_t, o_at);
  // x1 = x + gate_msa * (o @ wo + bo)  -> written to d_out (fp32)
  gemm_bt<2><<<dim3(32, 8), 256, 0, stream>>>(o_at, wo_t, bo, x, gmsa, out, 4096, 1024, 1024);

  // MLP branch (accumulates into d_out)
  ln_k<<<4096, 256, 0, stream>>>(out, ln2_g, ln2_b, h2);
  gemm_bt<1><<<dim3(32, 32), 256, 0, stream>>>(h2, w1_t, b1, nullptr, nullptr, g1, 4096, 4096, 1024);
  gemm_bt<3><<<dim3(32, 8), 256, 0, stream>>>(g1, w2_t, b2, nullptr, gmlp, out, 4096, 1024, 4096);
}

// Round 4
// 319.934 us; speedup vs baseline: 1.7605x; 1.1373x over previous
//
#include <hip/hip_runtime.h>

typedef unsigned short u16;
typedef __attribute__((ext_vector_type(4))) float f32x4;
typedef __attribute__((ext_vector_type(8))) short bf16x8;

#define DEV static __device__ __forceinline__

DEV float bf2f(u16 u) { unsigned int i = ((unsigned int)u) << 16; return __builtin_bit_cast(float, i); }
DEV u16 f2bf(float f) {
  unsigned int x = __builtin_bit_cast(unsigned int, f);
  x += 0x7fffu + ((x >> 16) & 1u);
  return (u16)(x >> 16);
}

DEV void gload16(const u16* g, u16* l) {
  __builtin_amdgcn_global_load_lds(
      (const __attribute__((address_space(1))) unsigned int*)g,
      (__attribute__((address_space(3))) unsigned int*)l, 16, 0, 0);
}

// ---------------- LayerNorm: fp32 in -> bf16 out (D=1024, one block per row) ----------------
__global__ __launch_bounds__(256) void ln_k(const float* __restrict__ x,
                                            const float* __restrict__ g,
                                            const float* __restrict__ b,
                                            u16* __restrict__ out) {
  const int row = blockIdx.x;
  const int t = threadIdx.x;
  const float4 v = *(const float4*)(x + (size_t)row * 1024 + t * 4);
  float s = v.x + v.y + v.z + v.w;
  float q = v.x * v.x + v.y * v.y + v.z * v.z + v.w * v.w;
#pragma unroll
  for (int m = 1; m < 64; m <<= 1) { s += __shfl_xor(s, m); q += __shfl_xor(q, m); }
  __shared__ float ss[4], qs[4];
  if ((t & 63) == 0) { ss[t >> 6] = s; qs[t >> 6] = q; }
  __syncthreads();
  s = ss[0] + ss[1] + ss[2] + ss[3];
  q = qs[0] + qs[1] + qs[2] + qs[3];
  const float mean = s * (1.0f / 1024.0f);
  const float var = q * (1.0f / 1024.0f) - mean * mean;
  const float rs = rsqrtf(var + 1e-6f);
  const float4 gv = *(const float4*)(g + t * 4);
  const float4 bv = *(const float4*)(b + t * 4);
  ushort4 o;
  o.x = f2bf((v.x - mean) * rs * gv.x + bv.x);
  o.y = f2bf((v.y - mean) * rs * gv.y + bv.y);
  o.z = f2bf((v.z - mean) * rs * gv.z + bv.z);
  o.w = f2bf((v.w - mean) * rs * gv.w + bv.w);
  *(ushort4*)(out + (size_t)row * 1024 + t * 4) = o;
}

// ---------------- weight transpose + cvt: src (K x N) f32 -> dst (N x K) bf16 ----------------
__global__ __launch_bounds__(256) void tcvt_k(const float* __restrict__ src,
                                              u16* __restrict__ dst, int K, int N) {
  __shared__ u16 tl[32][33];
  const int k0 = blockIdx.x * 32, n0 = blockIdx.y * 32;
  const int c = threadIdx.x & 31, r0 = threadIdx.x >> 5;
#pragma unroll
  for (int p = 0; p < 4; p++) {
    const int r = p * 8 + r0;
    tl[r][c] = f2bf(src[(size_t)(k0 + r) * N + n0 + c]);
  }
  __syncthreads();
#pragma unroll
  for (int p = 0; p < 4; p++) {
    const int r = p * 8 + r0;
    dst[(size_t)(n0 + r) * K + k0 + c] = tl[c][r];
  }
}

// ---------------- GEMM: C(MxN) = A(MxK,bf16) @ Bt(NxK,bf16)^T, fused epilogues ----------------
// 2-phase double-buffered K-loop (T3-minimal, m248): STAGE(next) -> compute(cur) ->
// one __syncthreads per iter (implicit vmcnt(0) drains the prefetch).
// TN=128: 4 waves in 2x2, acc[4][4]. TN=64: 4 waves stacked on M, acc[2][4].
// EPI 0: out bf16 = acc + bias
// EPI 1: out bf16 = gelu(acc + bias)
// EPI 2: out f32  = resid + gate[col]*(acc + bias)
// EPI 3: out f32 += gate[col]*(acc + bias)
template <int EPI, int TN>
__global__ __launch_bounds__(256) void gemm_bt(const u16* __restrict__ A,
                                               const u16* __restrict__ Bt,
                                               const float* __restrict__ bias,
                                               const float* __restrict__ resid,
                                               const float* __restrict__ gate,
                                               void* __restrict__ outv,
                                               int M, int N, int K) {
  constexpr int MI = (TN == 128) ? 4 : 2;   // m-frags per wave
  constexpr int WRS = (TN == 128) ? 64 : 32; // rows per wave
  __shared__ __align__(16) u16 lA[2][128 * 32];
  __shared__ __align__(16) u16 lB[2][TN * 32];
  const int tid = threadIdx.x;
  const int lane = tid & 63, wid = tid >> 6;
  const int l4 = lane >> 4, l15 = lane & 15;
  const int wr = (TN == 128) ? (wid >> 1) : wid;
  const int wc = (TN == 128) ? (wid & 1) : 0;
  const int mBase = blockIdx.x * 128;
  const int nBase = blockIdx.y * TN;

  f32x4 acc[MI][4];
#pragma unroll
  for (int i = 0; i < MI; i++)
#pragma unroll
    for (int j = 0; j < 4; j++)
#pragma unroll
      for (int e = 0; e < 4; e++) acc[i][j][e] = 0.f;

  const int sRow = tid >> 2;        // 0..63
  const int sCol = (tid & 3) * 8;   // u16 units, 16B chunks

#define STAGE(bufi, k0)                                                               \
  {                                                                                   \
    _Pragma("unroll") for (int p = 0; p < 2; p++)                                     \
        gload16(A + (size_t)(mBase + p * 64 + sRow) * K + (k0) + sCol,                \
                &lA[bufi][p * 2048 + wid * 512]);                                     \
    _Pragma("unroll") for (int p = 0; p < TN / 64; p++)                               \
        gload16(Bt + (size_t)(nBase + p * 64 + sRow) * K + (k0) + sCol,               \
                &lB[bufi][p * 2048 + wid * 512]);                                     \
  }

  const int nt = K >> 5;
  STAGE(0, 0);
  __syncthreads();
  int buf = 0;
  for (int it = 0; it < nt; ++it) {
    if (it + 1 < nt) STAGE(buf ^ 1, (it + 1) * 32);
    bf16x8 af[MI], bfr[4];
#pragma unroll
    for (int mi = 0; mi < MI; mi++)
      af[mi] = *(const bf16x8*)(&lA[buf][(wr * WRS + mi * 16 + l15) * 32 + l4 * 8]);
#pragma unroll
    for (int ni = 0; ni < 4; ni++)
      bfr[ni] = *(const bf16x8*)(&lB[buf][(wc * 64 + ni * 16 + l15) * 32 + l4 * 8]);
#pragma unroll
    for (int mi = 0; mi < MI; mi++)
#pragma unroll
      for (int ni = 0; ni < 4; ni++)
        acc[mi][ni] = __builtin_amdgcn_mfma_f32_16x16x32_bf16(af[mi], bfr[ni], acc[mi][ni], 0, 0, 0);
    __syncthreads();
    buf ^= 1;
  }
#undef STAGE

  u16* obf = (u16*)outv;
  float* of = (float*)outv;
#pragma unroll
  for (int mi = 0; mi < MI; mi++) {
#pragma unroll
    for (int ni = 0; ni < 4; ni++) {
      const int row0 = mBase + wr * WRS + mi * 16 + l4 * 4;
      const int col = nBase + wc * 64 + ni * 16 + l15;
      const float bb = bias[col];
#pragma unroll
      for (int r = 0; r < 4; r++) {
        const float v = acc[mi][ni][r] + bb;
        const size_t idx = (size_t)(row0 + r) * N + col;
        if (EPI == 0) {
          obf[idx] = f2bf(v);
        } else if (EPI == 1) {
          const float ge = 0.5f * v * (1.0f + erff(v * 0.70710678118654752f));
          obf[idx] = f2bf(ge);
        } else if (EPI == 2) {
          of[idx] = resid[idx] + gate[col] * v;
        } else {
          of[idx] = of[idx] + gate[col] * v;
        }
      }
    }
  }
}

// ---------------- RoPE + head-layout: qkv(4096x3072 bf16) -> q_r/k_r (B,H,L,hd) bf16 ----------------
// q additionally pre-scaled by 1/sqrt(hd) = 0.125 so attention uses raw dot products.
__global__ __launch_bounds__(256) void rope_k(const u16* __restrict__ qkv,
                                              u16* __restrict__ qr, u16* __restrict__ kr) {
  const int sel = blockIdx.y;  // 0 -> q, 1 -> k
  const int rid = blockIdx.x * 8 + (threadIdx.x >> 5);  // (b,h,t) row id, 0..65535
  const int i = threadIdx.x & 31;                       // pair index 0..31
  const int b = rid >> 15;
  const int h = (rid >> 11) & 15;
  const int t = rid & 2047;
  const u16* src = qkv + (size_t)(b * 2048 + t) * 3072 + sel * 1024 + h * 64 + 2 * i;
  const ushort2 uv = *(const ushort2*)src;
  const float x0 = bf2f(uv.x), x1 = bf2f(uv.y);
  const float inv = __expf(-(float)i * 0.28782313662425572f);  // ln(10000)/32
  float sn, cs;
  sincosf((float)t * inv, &sn, &cs);
  const float sc = sel ? 1.0f : 0.125f;
  ushort2 ov;
  ov.x = f2bf((x0 * cs - x1 * sn) * sc);
  ov.y = f2bf((x1 * cs + x0 * sn) * sc);
  *(ushort2*)((sel ? kr : qr) + (size_t)rid * 64 + 2 * i) = ov;
}

// ---------------- V layout: qkv cols 2048.. -> v_t (B,H,hd,L) bf16 (transposed) ----------------
__global__ __launch_bounds__(256) void vtrans_k(const u16* __restrict__ qkv, u16* __restrict__ vt) {
  __shared__ u16 tl[64][65];
  const int bh = blockIdx.x >> 5;
  const int t0 = (blockIdx.x & 31) * 64;
  const int b = bh >> 4, h = bh & 15;
  const int tid = threadIdx.x;
#pragma unroll
  for (int p = 0; p < 16; p++) {
    const int e = p * 256 + tid;
    const int tr = e >> 6, d = e & 63;
    tl[tr][d] = qkv[(size_t)(b * 2048 + t0 + tr) * 3072 + 2048 + h * 64 + d];
  }
  __syncthreads();
#pragma unroll
  for (int p = 0; p < 16; p++) {
    const int e = p * 256 + tid;
    const int dr = e >> 6, tc = e & 63;
    vt[(size_t)(bh * 64 + dr) * 2048 + t0 + tc] = tl[tc][dr];
  }
}

// ---------------- Flash attention: LDS-staged K/V (dbuf), 4 waves x 32 q-rows ----------------
// q,k: (B,H,L,hd) bf16 (q pre-scaled); vt: (B,H,hd,L) bf16 ; o: (B,L,D) bf16
__global__ __launch_bounds__(256) void attn_k(const u16* __restrict__ q,
                                              const u16* __restrict__ k,
                                              const u16* __restrict__ vt,
                                              u16* __restrict__ o) {
  const int bh = blockIdx.y;
  const int tid = threadIdx.x;
  const int wid = tid >> 6, lane = tid & 63;
  const int l4 = lane >> 4, l15 = lane & 15;
  const int qrow0 = blockIdx.x * 128 + wid * 32;

  __shared__ __align__(16) u16 kls[2][4096];   // K tile [64 kv][64 d], row-XOR-swizzled
  __shared__ __align__(16) u16 vls[2][4096];   // V^T tile [64 d][64 kv], row-XOR-swizzled
  __shared__ __align__(16) u16 pls[4][2048];   // per-wave P [32 q][64 kv], row-XOR-swizzled
  __shared__ __align__(16) float alds[4][32];

  // Q fragments: 2 q-sets x 2 d-halves
  const size_t qoff = ((size_t)bh * 2048 + qrow0) * 64;
  bf16x8 qf[2][2];
#pragma unroll
  for (int g = 0; g < 2; g++) {
    qf[g][0] = *(const bf16x8*)(q + qoff + (size_t)(g * 16 + l15) * 64 + l4 * 8);
    qf[g][1] = *(const bf16x8*)(q + qoff + (size_t)(g * 16 + l15) * 64 + 32 + l4 * 8);
  }

  float m0 = -1e30f, m1 = -1e30f, ls0 = 0.f, ls1 = 0.f;
  f32x4 oacc[2][4];
#pragma unroll
  for (int g = 0; g < 2; g++)
#pragma unroll
    for (int ni = 0; ni < 4; ni++)
#pragma unroll
      for (int e = 0; e < 4; e++) oacc[g][ni][e] = 0.f;

  const char* kg = (const char*)(k + (size_t)bh * 2048 * 64);   // K rows: 128 B
  const char* vg = (const char*)(vt + (size_t)bh * 64 * 2048);  // V^T rows: 4096 B
  // staging slots: s = pass*256 + tid ; row = s>>3 ; source col pre-swizzled
  const int sA = tid, sB = 256 + tid;
  const int rA = sA >> 3, cA = ((sA & 7) ^ (rA & 7)) << 4;
  const int rB = sB >> 3, cB = ((sB & 7) ^ (rB & 7)) << 4;
  u16* kd0 = &kls[0][(size_t)(wid * 64) * 8];
  u16* kd1 = &kls[0][(size_t)(256 + wid * 64) * 8];
  u16* vd0 = &vls[0][(size_t)(wid * 64) * 8];
  u16* vd1 = &vls[0][(size_t)(256 + wid * 64) * 8];

#define STAGE(bufi, kv0)                                                            \
  {                                                                                 \
    const int _o = (bufi)*4096;                                                     \
    gload16((const u16*)(kg + (size_t)((kv0) + rA) * 128 + cA), kd0 + _o);          \
    gload16((const u16*)(kg + (size_t)((kv0) + rB) * 128 + cB), kd1 + _o);          \
    gload16((const u16*)(vg + (size_t)rA * 4096 + (kv0)*2 + cA), vd0 + _o);         \
    gload16((const u16*)(vg + (size_t)rB * 4096 + (kv0)*2 + cB), vd1 + _o);         \
  }

  STAGE(0, 0);
  __syncthreads();

  char* P = (char*)pls[wid];
  float* AL = alds[wid];
  char* prow0 = P + l15 * 128;
  char* prow1 = P + (16 + l15) * 128;
  const int psw = (l15 & 7) << 4;

  int buf = 0;
  for (int it = 0; it < 32; ++it) {
    if (it < 31) STAGE(buf ^ 1, (it + 1) * 64);
    const char* K = (const char*)kls[buf];
    const char* V = (const char*)vls[buf];

    // ---- QK^T (swapped): s[g][kt][r] = S^T[kv=kt*16+l4*4+r][q=g*16+l15]
    f32x4 s0[4], s1[4];
#pragma unroll
    for (int kt = 0; kt < 4; kt++) {
      const int row = kt * 16 + l15;
      const int sw = (row & 7) << 4;
      const char* kr = K + row * 128;
      const bf16x8 kf0 = *(const bf16x8*)(kr + ((l4 * 16) ^ sw));
      const bf16x8 kf1 = *(const bf16x8*)(kr + ((64 + l4 * 16) ^ sw));
      f32x4 z0 = {0.f, 0.f, 0.f, 0.f}, z1 = {0.f, 0.f, 0.f, 0.f};
      z0 = __builtin_amdgcn_mfma_f32_16x16x32_bf16(kf0, qf[0][0], z0, 0, 0, 0);
      s0[kt] = __builtin_amdgcn_mfma_f32_16x16x32_bf16(kf1, qf[0][1], z0, 0, 0, 0);
      z1 = __builtin_amdgcn_mfma_f32_16x16x32_bf16(kf0, qf[1][0], z1, 0, 0, 0);
      s1[kt] = __builtin_amdgcn_mfma_f32_16x16x32_bf16(kf1, qf[1][1], z1, 0, 0, 0);
    }

    // ---- softmax (per q = l15 / 16+l15)
    float pm0 = s0[0][0], pm1 = s1[0][0];
#pragma unroll
    for (int kt = 0; kt < 4; kt++)
#pragma unroll
      for (int r = 0; r < 4; r++) {
        pm0 = fmaxf(pm0, s0[kt][r]);
        pm1 = fmaxf(pm1, s1[kt][r]);
      }
    pm0 = fmaxf(pm0, __shfl_xor(pm0, 16));
    pm0 = fmaxf(pm0, __shfl_xor(pm0, 32));
    pm1 = fmaxf(pm1, __shfl_xor(pm1, 16));
    pm1 = fmaxf(pm1, __shfl_xor(pm1, 32));
    const bool need = !__all((pm0 <= m0 + 8.0f) && (pm1 <= m1 + 8.0f));  // defer-max
    float al0 = 1.0f, al1 = 1.0f;
    if (need) {
      const float mn0 = fmaxf(m0, pm0), mn1 = fmaxf(m1, pm1);
      al0 = __expf(m0 - mn0); al1 = __expf(m1 - mn1);
      m0 = mn0; m1 = mn1;
      if (l4 == 0) { AL[l15] = al0; AL[16 + l15] = al1; }
    }
    float ps0 = 0.f, ps1 = 0.f;
#pragma unroll
    for (int kt = 0; kt < 4; kt++)
#pragma unroll
      for (int r = 0; r < 4; r++) {
        s0[kt][r] = __expf(s0[kt][r] - m0); ps0 += s0[kt][r];
        s1[kt][r] = __expf(s1[kt][r] - m1); ps1 += s1[kt][r];
      }
    ps0 += __shfl_xor(ps0, 16); ps0 += __shfl_xor(ps0, 32);
    ps1 += __shfl_xor(ps1, 16); ps1 += __shfl_xor(ps1, 32);
    ls0 = ls0 * al0 + ps0;
    ls1 = ls1 * al1 + ps1;

    // ---- P -> LDS (b64 writes, XOR-swizzled rows)
#pragma unroll
    for (int kt = 0; kt < 4; kt++) {
      uint2 w0, w1;
      w0.x = (unsigned)f2bf(s0[kt][0]) | ((unsigned)f2bf(s0[kt][1]) << 16);
      w0.y = (unsigned)f2bf(s0[kt][2]) | ((unsigned)f2bf(s0[kt][3]) << 16);
      w1.x = (unsigned)f2bf(s1[kt][0]) | ((unsigned)f2bf(s1[kt][1]) << 16);
      w1.y = (unsigned)f2bf(s1[kt][2]) | ((unsigned)f2bf(s1[kt][3]) << 16);
      *(uint2*)(prow0 + ((kt * 32 + l4 * 8) ^ psw)) = w0;
      *(uint2*)(prow1 + ((kt * 32 + l4 * 8) ^ psw)) = w1;
    }
    asm volatile("s_waitcnt lgkmcnt(0)" ::: "memory");
    const bf16x8 pa00 = *(const bf16x8*)(prow0 + ((l4 * 16) ^ psw));
    const bf16x8 pa01 = *(const bf16x8*)(prow0 + ((64 + l4 * 16) ^ psw));
    const bf16x8 pa10 = *(const bf16x8*)(prow1 + ((l4 * 16) ^ psw));
    const bf16x8 pa11 = *(const bf16x8*)(prow1 + ((64 + l4 * 16) ^ psw));
    if (need) {
      const f32x4 a0 = *(const f32x4*)((const char*)AL + l4 * 16);
      const f32x4 a1 = *(const f32x4*)((const char*)AL + 64 + l4 * 16);
#pragma unroll
      for (int ni = 0; ni < 4; ni++) { oacc[0][ni] *= a0; oacc[1][ni] *= a1; }
    }

    // ---- PV from LDS V^T tile
#pragma unroll
    for (int ni = 0; ni < 4; ni++) {
      const int vrow = ni * 16 + l15;
      const int vsw = (vrow & 7) << 4;
      const char* vr = V + vrow * 128;
      const bf16x8 v0 = *(const bf16x8*)(vr + ((l4 * 16) ^ vsw));
      const bf16x8 v1 = *(const bf16x8*)(vr + ((64 + l4 * 16) ^ vsw));
      oacc[0][ni] = __builtin_amdgcn_mfma_f32_16x16x32_bf16(pa00, v0, oacc[0][ni], 0, 0, 0);
      oacc[0][ni] = __builtin_amdgcn_mfma_f32_16x16x32_bf16(pa01, v1, oacc[0][ni], 0, 0, 0);
      oacc[1][ni] = __builtin_amdgcn_mfma_f32_16x16x32_bf16(pa10, v0, oacc[1][ni], 0, 0, 0);
      oacc[1][ni] = __builtin_amdgcn_mfma_f32_16x16x32_bf16(pa11, v1, oacc[1][ni], 0, 0, 0);
    }
    __syncthreads();  // drains vmcnt(0): staged tile ready; old buf free
    buf ^= 1;
  }
#undef STAGE

  if (l4 == 0) { AL[l15] = 1.0f / ls0; AL[16 + l15] = 1.0f / ls1; }
  asm volatile("s_waitcnt lgkmcnt(0)" ::: "memory");
  const f32x4 iv0 = *(const f32x4*)((const char*)AL + l4 * 16);
  const f32x4 iv1 = *(const f32x4*)((const char*)AL + 64 + l4 * 16);
  const int b = bh >> 4, h = bh & 15;
#pragma unroll
  for (int g = 0; g < 2; g++) {
#pragma unroll
    for (int r = 0; r < 4; r++) {
      const size_t row = (size_t)b * 2048 + qrow0 + g * 16 + l4 * 4 + r;
      const float iv = g ? iv1[r] : iv0[r];
#pragma unroll
      for (int ni = 0; ni < 4; ni++)
        o[row * 1024 + h * 64 + ni * 16 + l15] = f2bf(oacc[g][ni][r] * iv);
    }
  }
}

extern "C" void kernel_launch(void* const* d_in, const int* in_sizes, int n_in,
                              void* d_out, int out_size, void* d_ws, size_t ws_size,
                              hipStream_t stream) {
  (void)in_sizes; (void)n_in; (void)out_size; (void)ws_size;
  const float* x     = (const float*)d_in[0];
  const float* ln1_g = (const float*)d_in[1];
  const float* ln1_b = (const float*)d_in[2];
  const float* wq    = (const float*)d_in[3];
  const float* bq    = (const float*)d_in[4];
  const float* wk    = (const float*)d_in[5];
  const float* bk    = (const float*)d_in[6];
  const float* wv    = (const float*)d_in[7];
  const float* bv    = (const float*)d_in[8];
  const float* wo    = (const float*)d_in[9];
  const float* bo    = (const float*)d_in[10];
  const float* ln2_g = (const float*)d_in[11];
  const float* ln2_b = (const float*)d_in[12];
  const float* w1    = (const float*)d_in[13];
  const float* b1    = (const float*)d_in[14];
  const float* w2    = (const float*)d_in[15];
  const float* b2    = (const float*)d_in[16];
  const float* gmsa  = (const float*)d_in[17];
  const float* gmlp  = (const float*)d_in[18];
  float* out = (float*)d_out;

  char* w = (char*)d_ws;
  auto alloc = [&](size_t bytes) {
    char* p = w;
    w += (bytes + 255) & ~(size_t)255;
    return p;
  };
  u16* h1     = (u16*)alloc(4096UL * 1024 * 2);
  u16* wqkv_t = (u16*)alloc(3072UL * 1024 * 2);
  u16* wo_t   = (u16*)alloc(1024UL * 1024 * 2);
  u16* w1_t   = (u16*)alloc(4096UL * 1024 * 2);
  u16* w2_t   = (u16*)alloc(1024UL * 4096 * 2);
  float* bqkv = (float*)alloc(3072UL * 4);
  u16* qkv    = (u16*)alloc(4096UL * 3072 * 2);
  u16* q_r    = (u16*)alloc(65536UL * 64 * 2);
  u16* k_r    = (u16*)alloc(65536UL * 64 * 2);
  u16* v_t    = (u16*)alloc(65536UL * 64 * 2);
  u16* o_at   = (u16*)alloc(4096UL * 1024 * 2);
  u16* h2     = (u16*)alloc(4096UL * 1024 * 2);
  u16* g1     = (u16*)alloc(4096UL * 4096 * 2);

  // weights -> bf16, transposed to (N x K); qkv packed [wq; wk; wv]
  tcvt_k<<<dim3(32, 32), 256, 0, stream>>>(wq, wqkv_t, 1024, 1024);
  tcvt_k<<<dim3(32, 32), 256, 0, stream>>>(wk, wqkv_t + 1024 * 1024, 1024, 1024);
  tcvt_k<<<dim3(32, 32), 256, 0, stream>>>(wv, wqkv_t + 2048 * 1024, 1024, 1024);
  tcvt_k<<<dim3(32, 32), 256, 0, stream>>>(wo, wo_t, 1024, 1024);
  tcvt_k<<<dim3(32, 128), 256, 0, stream>>>(w1, w1_t, 1024, 4096);
  tcvt_k<<<dim3(128, 32), 256, 0, stream>>>(w2, w2_t, 4096, 1024);
  hipMemcpyAsync(bqkv,        bq, 1024 * sizeof(float), hipMemcpyDeviceToDevice, stream);
  hipMemcpyAsync(bqkv + 1024, bk, 1024 * sizeof(float), hipMemcpyDeviceToDevice, stream);
  hipMemcpyAsync(bqkv + 2048, bv, 1024 * sizeof(float), hipMemcpyDeviceToDevice, stream);

  // attention branch
  ln_k<<<4096, 256, 0, stream>>>(x, ln1_g, ln1_b, h1);
  gemm_bt<0, 128><<<dim3(32, 24), 256, 0, stream>>>(h1, wqkv_t, bqkv, nullptr, nullptr, qkv, 4096, 3072, 1024);
  rope_k<<<dim3(8192, 2), 256, 0, stream>>>(qkv, q_r, k_r);
  vtrans_k<<<1024, 256, 0, stream>>>(qkv, v_t);
  attn_k<<<dim3(16, 32), 256, 0, stream>>>(q_r, k_r, v_t, o_at);
  // x1 = x + gate_msa * (o @ wo + bo)  -> written to d_out (fp32)
  gemm_bt<2, 64><<<dim3(32, 16), 256, 0, stream>>>(o_at, wo_t, bo, x, gmsa, out, 4096, 1024, 1024);

  // MLP branch (accumulates into d_out)
  ln_k<<<4096, 256, 0, stream>>>(out, ln2_g, ln2_b, h2);
  gemm_bt<1, 128><<<dim3(32, 32), 256, 0, stream>>>(h2, w1_t, b1, nullptr, nullptr, g1, 4096, 4096, 1024);
  gemm_bt<3, 64><<<dim3(32, 16), 256, 0, stream>>>(g1, w2_t, b2, nullptr, gmlp, out, 4096, 1024, 4096);
}